// Round 5
// baseline (346.973 us; speedup 1.0000x reference)
//
#include <hip/hip_runtime.h>

// LIF scan: x[B,T,N] f32 -> spikes[B,T,N] f32
//   v = v + (x - v)/2 ; s = (v >= 1) ; v = s ? 0 : v
// Sequential in t only; B*N independent chains. Memory-bound streaming.
// HBM traffic ~315 MB (write 210 MB + fetch ~105 MB; LLC holds half the
// input) -> floor ~50 us. Harness adds ~255 us fixed (fills/restore).
//
// R1: float4, 4 waves/CU, unroll-8            -> kernel ~82 us
// R3: manual rotating prefetch + nt + branch  -> 151 us REGRESSION
// R4: float2, 8 waves/CU, unroll-8            -> kernel ~88 us (= R1)
//     occupancy 4->8 waves didn't move it => stalls are load-behind-store
//     vmcnt retirement, not raw in-flight capacity.
// R5: scalar float chains -> 4096 waves = 16 waves/CU, double the TLP to
//     hide the shared-vmcnt store-drain stalls. Coalescing unchanged
//     (64 lanes x 4 B contiguous); VALU still <25%.

constexpr int B = 64;
constexpr int T = 200;
constexpr int N = 4096;

__global__ __launch_bounds__(256) void lif_kernel(const float* __restrict__ x,
                                                  float* __restrict__ out) {
    const int idx = blockIdx.x * blockDim.x + threadIdx.x;  // 0 .. B*N-1
    const int b = idx >> 12;         // idx / N
    const int n = idx & (N - 1);     // idx % N

    const float* __restrict__ xp = x + (size_t)b * (T * N) + n;
    float* __restrict__ op = out + (size_t)b * (T * N) + n;

    float v = 0.0f;

    // Branch-free unrolled body; the 8 loads per group are independent of
    // the serial v-chain so the compiler clusters them.
#pragma unroll 8
    for (int t = 0; t < T; ++t) {
        const float xv = xp[t * N];

        // v = v + (x - v) * 0.5f  -- *0.5 exact; bit-identical to the
        // f32 numpy reference with or without fma contraction.
        v = v + (xv - v) * 0.5f;

        const float s = (v >= 1.0f) ? 1.0f : 0.0f;
        v = (v >= 1.0f) ? 0.0f : v;

        op[t * N] = s;
    }
}

extern "C" void kernel_launch(void* const* d_in, const int* in_sizes, int n_in,
                              void* d_out, int out_size, void* d_ws, size_t ws_size,
                              hipStream_t stream) {
    const float* x = (const float*)d_in[0];  // [B,T,N] f32
    // d_in[1] (threshold, 1xN) is unused by the reference math.
    float* out = (float*)d_out;

    const int threads = B * N;          // 262144 scalar chains
    const int block = 256;
    const int grid = threads / block;   // 1024 blocks -> 4 blocks/CU, 16 waves/CU
    lif_kernel<<<grid, block, 0, stream>>>(x, out);
}

// Round 6
// 344.212 us; speedup vs baseline: 1.0080x; 1.0080x over previous
//
#include <hip/hip_runtime.h>

// LIF scan: x[B,T,N] f32 -> spikes[B,T,N] f32
//   v = v + (x - v)/2 ; s = (v >= 1) ; v = s ? 0 : v
// Sequential in t only; B*N independent chains. Memory-bound streaming.
// HBM traffic ~315 MB (write 210 MB + fetch ~105 MB; LLC holds half of x)
// -> floor ~50-67 us. Harness adds ~255 us fixed (restore/poison fills).
//
// R1: float4, unroll-8                  -> kernel ~82 us (total 337)
// R3: per-elem rotating prefetch + nt   -> 151 us REGRESSION
// R4: float2, 8 waves/CU                -> ~88 us (total 343)
// R5: scalar, 16 waves/CU               -> ~92 us (total 347)
//   => occupancy irrelevant; width wins. Bottleneck theory: loads of group
//      g+1 are issued AFTER stores of group g (shared in-order vmcnt), so
//      each group's load-wait drains the store queue.
// R6: group-level double buffer -- issue group g+1's 8 loads BEFORE group
//     g's 8 stores; load-wait becomes vmcnt(8) with a full group of
//     compute as head start, never waiting on store completion. nt on
//     stores only (zero reuse; preserve x's LLC residency).

typedef float vfloat4 __attribute__((ext_vector_type(4)));

constexpr int B = 64;
constexpr int T = 200;
constexpr int N = 4096;
constexpr int N4 = N / 4;   // 1024 float4 per (b,t) row
constexpr int G = 8;        // group size (T = 8 * 25)
constexpr int NG = T / G;   // 25 groups

__global__ __launch_bounds__(256) void lif_kernel(const vfloat4* __restrict__ x,
                                                  vfloat4* __restrict__ out) {
    const int idx = blockIdx.x * blockDim.x + threadIdx.x;  // 0 .. B*N4-1
    const int b = idx >> 10;          // idx / N4
    const int n = idx & (N4 - 1);     // idx % N4

    const vfloat4* __restrict__ xp = x + (size_t)b * (T * N4) + n;
    vfloat4* __restrict__ op = out + (size_t)b * (T * N4) + n;

    vfloat4 buf[G], nbuf[G];
#pragma unroll
    for (int j = 0; j < G; ++j) buf[j] = xp[j * N4];

    vfloat4 v = {0.0f, 0.0f, 0.0f, 0.0f};

    for (int g = 0; g < NG - 1; ++g) {
        const int base = g * G;

        // Prefetch group g+1 FIRST -- these loads precede group g's stores
        // in issue order, so their completion never waits on stores.
#pragma unroll
        for (int j = 0; j < G; ++j) nbuf[j] = xp[(base + G + j) * N4];

        // Compute + store group g.
#pragma unroll
        for (int j = 0; j < G; ++j) {
            const vfloat4 xv = buf[j];
            // v = v + (x - v) * 0.5f  -- *0.5 exact; bit-identical to the
            // f32 numpy reference with or without fma contraction.
            v.x = v.x + (xv.x - v.x) * 0.5f;
            v.y = v.y + (xv.y - v.y) * 0.5f;
            v.z = v.z + (xv.z - v.z) * 0.5f;
            v.w = v.w + (xv.w - v.w) * 0.5f;

            vfloat4 s;
            s.x = (v.x >= 1.0f) ? 1.0f : 0.0f;
            s.y = (v.y >= 1.0f) ? 1.0f : 0.0f;
            s.z = (v.z >= 1.0f) ? 1.0f : 0.0f;
            s.w = (v.w >= 1.0f) ? 1.0f : 0.0f;
            v.x = (v.x >= 1.0f) ? 0.0f : v.x;
            v.y = (v.y >= 1.0f) ? 0.0f : v.y;
            v.z = (v.z >= 1.0f) ? 0.0f : v.z;
            v.w = (v.w >= 1.0f) ? 0.0f : v.w;

            __builtin_nontemporal_store(s, &op[(base + j) * N4]);
        }

#pragma unroll
        for (int j = 0; j < G; ++j) buf[j] = nbuf[j];
    }

    // Peeled last group (no prefetch).
    {
        const int base = (NG - 1) * G;
#pragma unroll
        for (int j = 0; j < G; ++j) {
            const vfloat4 xv = buf[j];
            v.x = v.x + (xv.x - v.x) * 0.5f;
            v.y = v.y + (xv.y - v.y) * 0.5f;
            v.z = v.z + (xv.z - v.z) * 0.5f;
            v.w = v.w + (xv.w - v.w) * 0.5f;

            vfloat4 s;
            s.x = (v.x >= 1.0f) ? 1.0f : 0.0f;
            s.y = (v.y >= 1.0f) ? 1.0f : 0.0f;
            s.z = (v.z >= 1.0f) ? 1.0f : 0.0f;
            s.w = (v.w >= 1.0f) ? 1.0f : 0.0f;
            v.x = (v.x >= 1.0f) ? 0.0f : v.x;
            v.y = (v.y >= 1.0f) ? 0.0f : v.y;
            v.z = (v.z >= 1.0f) ? 0.0f : v.z;
            v.w = (v.w >= 1.0f) ? 0.0f : v.w;

            __builtin_nontemporal_store(s, &op[(base + j) * N4]);
        }
    }
}

extern "C" void kernel_launch(void* const* d_in, const int* in_sizes, int n_in,
                              void* d_out, int out_size, void* d_ws, size_t ws_size,
                              hipStream_t stream) {
    const vfloat4* x = (const vfloat4*)d_in[0];  // [B,T,N] f32
    // d_in[1] (threshold, 1xN) is unused by the reference math.
    vfloat4* out = (vfloat4*)d_out;

    const int threads = B * N4;         // 65536 float4 chains
    const int block = 256;
    const int grid = threads / block;   // 256 blocks
    lif_kernel<<<grid, block, 0, stream>>>(x, out);
}